// Round 6
// baseline (324.175 us; speedup 1.0000x reference)
//
#include <hip/hip_runtime.h>

#define NAGENT 64
#define HID    128
#define TOBS   8
#define PREDL  12
#define NTHR   1024
#define XP     264           // sh_X row pitch (ushort)
#define PP     264
#define S2P    264

typedef __attribute__((ext_vector_type(8))) short bf16x8;
typedef __attribute__((ext_vector_type(4))) short bf16x4;
typedef __attribute__((ext_vector_type(4))) float f32x4;
typedef __attribute__((ext_vector_type(4))) int   i32x4;

__device__ __forceinline__ unsigned short f2bf(float f) {
    unsigned int x = __float_as_uint(f);
    unsigned int r = (x + 0x7fffu + ((x >> 16) & 1u)) >> 16;   // RNE
    return (unsigned short)r;
}
__device__ __forceinline__ float bf2f(unsigned short u) {
    return __uint_as_float(((unsigned int)u) << 16);
}
__device__ __forceinline__ float sigmf(float x) {
    return __builtin_amdgcn_rcpf(1.0f + __expf(-x));
}
__device__ __forceinline__ float tanhf_fast(float x) {
    x = fminf(fmaxf(x, -15.0f), 15.0f);
    float e = __expf(2.0f * x);
    return (e - 1.0f) * __builtin_amdgcn_rcpf(e + 1.0f);
}

// ---------------- prep: pack weights into bf16 MFMA B-fragment layouts ----------------
// wd (D): B[k][n], k 0..255 = [et|at|h], n 0..511 = g*128+d (gate-major).
//   idx = ((nt*8+kt)*64+l)*8+e ; k = kt*32+(l>>4)*8+e ; n = nt*16+(l&15)
// wb (B): B[k][r], k 0..127 (h), r = e*4+g (16 nt x 4 kt)
// wp (proj): B[k][n], k 0..127 (h), n 0..15 (cols >=5 zero); hi (frags 0..3) + lo (4..7)
__global__ void prep_weights(const float* __restrict__ Wih, const float* __restrict__ Whh,
                             const float* __restrict__ socW, const float* __restrict__ predW,
                             unsigned short* __restrict__ wd, unsigned short* __restrict__ wb,
                             unsigned short* __restrict__ wp) {
    int idx = blockIdx.x * 256 + threadIdx.x;
    if (idx < 131072) {
        int e = idx & 7, l = (idx >> 3) & 63, t = idx >> 9;   // t = nt*8+kt
        int kt = t & 7, nt = t >> 3;
        int k = kt * 32 + ((l >> 4) << 3) + e;
        int n = nt * 16 + (l & 15);                           // n = g*128+d
        float v = (k < 128) ? Wih[n * 128 + k] : Whh[n * 128 + (k - 128)];
        wd[idx] = f2bf(v);
    } else if (idx < 163840) {
        int i2 = idx - 131072;
        int e = i2 & 7, l = (i2 >> 3) & 63, t = i2 >> 9;      // t = nt*4+kt
        int kt = t & 3, nt = t >> 2;
        int k = kt * 32 + ((l >> 4) << 3) + e;
        int r = nt * 16 + (l & 15);
        wb[i2] = f2bf(socW[(r >> 2) * 512 + (r & 3) * 128 + k]);
    } else if (idx < 167936) {
        int i3 = idx - 163840;
        int e = i3 & 7, l = (i3 >> 3) & 63, f = i3 >> 9;      // f = half*4+kt
        int kt = f & 3, half = f >> 2;
        int k = kt * 32 + ((l >> 4) << 3) + e;
        int n = l & 15;
        float v = (n < 5) ? predW[n * 128 + k] : 0.0f;
        unsigned short hi = f2bf(v);
        wp[i3] = half ? f2bf(v - bf2f(hi)) : hi;
    }
}

// ---------------- main: one block per 64-agent scene, 16 waves ----------------
// __launch_bounds__(1024, 4): 4 waves/EU = exactly one block/CU -> VGPR budget 128.
// (Plain __launch_bounds__(1024) let the allocator cap at 64 VGPR and spill ~1.7MB
//  of scratch per launch -- WRITE_SIZE 2064KB vs 344KB of real output. R5 lesson.)
__global__ __launch_bounds__(NTHR, 4) void social_lstm_mfma(
    const float* __restrict__ past_traj, const float* __restrict__ past_traj_rel,
    const int* __restrict__ ts_mask, const int* __restrict__ scene_in,
    const float* __restrict__ pos_W, const float* __restrict__ pos_b,
    const float* __restrict__ soc_b,
    const float* __restrict__ bih, const float* __restrict__ bhh,
    const float* __restrict__ h0, const float* __restrict__ c0,
    const float* __restrict__ pred_b,
    const unsigned short* __restrict__ wd, const unsigned short* __restrict__ wb,
    const unsigned short* __restrict__ wp,
    float* __restrict__ out)
{
    __shared__ __align__(16) unsigned short sh_X[NAGENT][XP];   // 0..63 et | 64..127 at | 128..255 h
    __shared__ __align__(16) unsigned short sh_P[NAGENT][PP];   // P[i][g*64+j] bf16 0/1
    __shared__ __align__(16) unsigned short sh_S2[NAGENT][S2P]; // S2[e][g*64+j] bf16
    __shared__ float sh_px[NAGENT], sh_py[NAGENT], sh_rx[NAGENT], sh_ry[NAGENT];
    __shared__ float sh_o[5][NAGENT];
    __shared__ __align__(16) int sh_act[NAGENT];
    __shared__ int sh_scene[NAGENT];

    const int tid  = threadIdx.x;
    const int lane = tid & 63;
    const int wv   = __builtin_amdgcn_readfirstlane(tid >> 6);  // 0..15
    const int gbase = blockIdx.x * NAGENT;
    const int c16 = lane & 15;
    const int q4  = lane >> 4;

    // wave roles
    const int sub8 = wv & 7;      // D: gate-free n-group ngd | B: r-tile pair ntp
    const int mjg  = wv >> 3;     // M-half (agents 32*mjg .. +31) for D and B
    const int dim  = sub8 * 16 + c16;          // this thread's hidden dim (D pointwise)

    // ---- Phase-B weights resident (8 frags = 32 VGPR) ----
    bf16x8 wbf[2][4];
    {
        const bf16x8* wbv = (const bf16x8*)wb;
        #pragma unroll
        for (int s = 0; s < 2; ++s)
            #pragma unroll
            for (int kt = 0; kt < 4; ++kt)
                wbf[s][kt] = wbv[((2 * sub8 + s) * 4 + kt) * 64 + lane];
    }
    const float bs0 = bih[0 * 128 + dim] + bhh[0 * 128 + dim];
    const float bs1 = bih[1 * 128 + dim] + bhh[1 * 128 + dim];
    const float bs2 = bih[2 * 128 + dim] + bhh[2 * 128 + dim];
    const float bs3 = bih[3 * 128 + dim] + bhh[3 * 128 + dim];
    float c_reg[8];
    {
        const float cz = c0[dim];
        #pragma unroll
        for (int u = 0; u < 8; ++u) c_reg[u] = cz;
    }
    for (int p = tid; p < NAGENT * HID; p += NTHR) {
        int a = p >> 7, d = p & 127;
        sh_X[a][128 + d] = f2bf(h0[d]);
    }
    if (tid < NAGENT) {
        sh_scene[tid] = scene_in[gbase + tid];
        const int ig = gbase + tid;
        sh_px[tid] = past_traj[(ig * TOBS + 0) * 2 + 0];
        sh_py[tid] = past_traj[(ig * TOBS + 0) * 2 + 1];
        sh_rx[tid] = past_traj_rel[(ig * TOBS + 0) * 2 + 0];
        sh_ry[tid] = past_traj_rel[(ig * TOBS + 0) * 2 + 1];
        sh_act[tid] = (ts_mask[ig * TOBS + 0] == 1) ? 1 : 0;
    }
    __syncthreads();

    for (int step = 0; step < TOBS + PREDL; ++step) {
        if (step >= TOBS) {
            // ---- proj (waves 0..3, MFMA, pred_W bf16 hi+lo): o = h @ predW^T + pred_b ----
            if (wv < 4) {
                const bf16x8* wpv = (const bf16x8*)wp;
                f32x4 pa = (f32x4){0.f, 0.f, 0.f, 0.f};
                #pragma unroll
                for (int kt = 0; kt < 4; ++kt) {
                    const bf16x8 a = *(const bf16x8*)&sh_X[wv * 16 + c16][128 + kt * 32 + q4 * 8];
                    pa = __builtin_amdgcn_mfma_f32_16x16x32_bf16(a, wpv[kt * 64 + lane], pa, 0, 0, 0);
                    pa = __builtin_amdgcn_mfma_f32_16x16x32_bf16(a, wpv[(4 + kt) * 64 + lane], pa, 0, 0, 0);
                }
                if (c16 < 5) {
                    const float pb = pred_b[c16];
                    #pragma unroll
                    for (int rr = 0; rr < 4; ++rr)
                        sh_o[c16][wv * 16 + q4 * 4 + rr] = pa[rr] + pb;
                }
            }
            __syncthreads();
            if (tid < NAGENT) {
                const int i = tid;
                const float rx = sh_o[0][i], ry = sh_o[1][i];
                const float px = sh_px[i] + rx, py = sh_py[i] + ry;
                sh_px[i] = px; sh_py[i] = py;
                sh_rx[i] = rx; sh_ry[i] = ry;
                const float m = sh_act[i] ? 1.0f : 0.0f;
                const int p = step - TOBS;
                const int ig = gbase + i;
                float* po = out + (ig * PREDL + p) * 5;
                #pragma unroll
                for (int q = 0; q < 5; ++q) po[q] = m * sh_o[q][i];
                float* pt = out + 61440 + (ig * PREDL + p) * 2;
                pt[0] = m * px; pt[1] = m * py;
            }
            __syncthreads();
        }

        // ==== R1: Phase A (P one-hot), et, Phase B (S2 via MFMA, resident weights) ====
        #pragma unroll
        for (int it = 0; it < 4; ++it) {
            const int p = it * NTHR + tid;
            const int i = p >> 6, j = p & 63;     // i wave-uniform, j = lane
            const float dx = sh_px[j] - sh_px[i];
            const float dy = sh_py[j] - sh_py[i];
            const bool within = (dx < 0.99f) & (dx > -0.99f) & (dy < 0.99f) & (dy > -0.99f);
            const bool pair = within && (i != j) && (sh_scene[i] == sh_scene[j])
                              && sh_act[i] && sh_act[j];
            const int gid = ((dx >= 0.f) ? 2 : 0) + ((dy >= 0.f) ? 1 : 0);
            #pragma unroll
            for (int g = 0; g < 4; ++g)
                sh_P[i][g * 64 + j] = (pair && gid == g) ? (unsigned short)0x3f80
                                                         : (unsigned short)0;
        }
        if (wv < 8) {   // et: wave wv -> embed dims wv*8..+7, one b128 write per lane
            const float rx = sh_rx[lane], ry = sh_ry[lane];
            bf16x8 ev;
            #pragma unroll
            for (int u = 0; u < 8; ++u) {
                const int e = wv * 8 + u;
                ev[u] = (short)f2bf(fmaxf(pos_b[e] + rx * pos_W[2 * e] + ry * pos_W[2 * e + 1], 0.f));
            }
            *(bf16x8*)&sh_X[lane][wv * 8] = ev;
        }
        {   // Phase B: wave (mjg, ntp=sub8) -> r-tiles {2ntp,2ntp+1}, agents mjg-half
            f32x4 bac[2][2];   // [mjl][s]
            #pragma unroll
            for (int a = 0; a < 2; ++a) { bac[a][0] = (f32x4){0,0,0,0}; bac[a][1] = (f32x4){0,0,0,0}; }
            #pragma unroll
            for (int kt = 0; kt < 4; ++kt) {
                const bf16x8 a0 = *(const bf16x8*)&sh_X[(2 * mjg + 0) * 16 + c16][128 + kt * 32 + q4 * 8];
                const bf16x8 a1 = *(const bf16x8*)&sh_X[(2 * mjg + 1) * 16 + c16][128 + kt * 32 + q4 * 8];
                #pragma unroll
                for (int s = 0; s < 2; ++s) {
                    bac[0][s] = __builtin_amdgcn_mfma_f32_16x16x32_bf16(a0, wbf[s][kt], bac[0][s], 0, 0, 0);
                    bac[1][s] = __builtin_amdgcn_mfma_f32_16x16x32_bf16(a1, wbf[s][kt], bac[1][s], 0, 0, 0);
                }
            }
            #pragma unroll
            for (int mjl = 0; mjl < 2; ++mjl)
                #pragma unroll
                for (int s = 0; s < 2; ++s) {
                    const int r = (2 * sub8 + s) * 16 + c16;
                    const int e = r >> 2, g = r & 3;
                    bf16x4 pk;
                    #pragma unroll
                    for (int i = 0; i < 4; ++i) pk[i] = (short)f2bf(bac[mjl][s][i]);
                    *(bf16x4*)&sh_S2[e][g * 64 + (2 * mjg + mjl) * 16 + q4 * 4] = pk;
                }
        }
        __syncthreads();

        // ==== R2: C2 (MFMA): at = relu(P @ S2^T + soc_b); wave = one 16x16 tile ====
        {
            const int mt = wv & 3, nt = wv >> 2;
            f32x4 cac = (f32x4){0.f, 0.f, 0.f, 0.f};
            #pragma unroll
            for (int kt = 0; kt < 8; ++kt) {
                const bf16x8 a = *(const bf16x8*)&sh_P[mt * 16 + c16][kt * 32 + q4 * 8];
                const bf16x8 b = *(const bf16x8*)&sh_S2[nt * 16 + c16][kt * 32 + q4 * 8];
                cac = __builtin_amdgcn_mfma_f32_16x16x32_bf16(a, b, cac, 0, 0, 0);
            }
            const int e = nt * 16 + c16;
            const float sb = soc_b[e];
            #pragma unroll
            for (int rr = 0; rr < 4; ++rr)
                sh_X[mt * 16 + q4 * 4 + rr][64 + e] = f2bf(fmaxf(cac[rr] + sb, 0.f));
        }
        __syncthreads();

        // ==== R3: D (MFMA, gate-major, B streamed from L2) + in-lane pointwise ====
        float hn_st[8];
        unsigned int hm = 0;
        {
            const bf16x8* wdv = (const bf16x8*)wd;
            f32x4 acc[2][4];   // [mjl][g]
            #pragma unroll
            for (int a = 0; a < 2; ++a)
                #pragma unroll
                for (int g = 0; g < 4; ++g) acc[a][g] = (f32x4){0.f, 0.f, 0.f, 0.f};
            #pragma unroll 2
            for (int kt = 0; kt < 8; ++kt) {
                const bf16x8 a0 = *(const bf16x8*)&sh_X[(2 * mjg + 0) * 16 + c16][kt * 32 + q4 * 8];
                const bf16x8 a1 = *(const bf16x8*)&sh_X[(2 * mjg + 1) * 16 + c16][kt * 32 + q4 * 8];
                #pragma unroll
                for (int g = 0; g < 4; ++g) {
                    const bf16x8 b = wdv[((g * 8 + sub8) * 8 + kt) * 64 + lane];
                    acc[0][g] = __builtin_amdgcn_mfma_f32_16x16x32_bf16(a0, b, acc[0][g], 0, 0, 0);
                    acc[1][g] = __builtin_amdgcn_mfma_f32_16x16x32_bf16(a1, b, acc[1][g], 0, 0, 0);
                }
            }
            #pragma unroll
            for (int mjl = 0; mjl < 2; ++mjl) {
                const i32x4 a4 = *(const i32x4*)&sh_act[(2 * mjg + mjl) * 16 + q4 * 4];
                #pragma unroll
                for (int rr = 0; rr < 4; ++rr) {
                    const float zi = acc[mjl][0][rr] + bs0;
                    const float zf = acc[mjl][1][rr] + bs1;
                    const float zg = acc[mjl][2][rr] + bs2;
                    const float zo = acc[mjl][3][rr] + bs3;
                    const float cold = c_reg[mjl * 4 + rr];
                    const float cn = sigmf(zf) * cold + sigmf(zi) * tanhf_fast(zg);
                    const float hn = sigmf(zo) * tanhf_fast(cn);
                    const bool act = a4[rr] != 0;
                    c_reg[mjl * 4 + rr] = act ? cn : cold;
                    hn_st[mjl * 4 + rr] = hn;
                    hm |= (act ? 1u : 0u) << (mjl * 4 + rr);
                }
            }
        }
        __syncthreads();   // all waves done reading sh_X before h overwrite

        // ==== h write-back (+ next obs frame load) ====
        #pragma unroll
        for (int u = 0; u < 8; ++u) {
            if (hm & (1u << u)) {
                const int mjl = u >> 2, rr = u & 3;
                sh_X[(2 * mjg + mjl) * 16 + q4 * 4 + rr][128 + dim] = f2bf(hn_st[u]);
            }
        }
        if (step + 1 < TOBS && tid < NAGENT) {
            const int ig = gbase + tid;
            sh_px[tid] = past_traj[(ig * TOBS + step + 1) * 2 + 0];
            sh_py[tid] = past_traj[(ig * TOBS + step + 1) * 2 + 1];
            sh_rx[tid] = past_traj_rel[(ig * TOBS + step + 1) * 2 + 0];
            sh_ry[tid] = past_traj_rel[(ig * TOBS + step + 1) * 2 + 1];
            sh_act[tid] = (ts_mask[ig * TOBS + step + 1] == 1) ? 1 : 0;
        }
        __syncthreads();
    }
}

extern "C" void kernel_launch(void* const* d_in, const int* in_sizes, int n_in,
                              void* d_out, int out_size, void* d_ws, size_t ws_size,
                              hipStream_t stream) {
    (void)in_sizes; (void)n_in; (void)out_size; (void)ws_size;
    unsigned short* wd = (unsigned short*)d_ws;            // 131072 ushorts
    unsigned short* wb = wd + 131072;                      //  32768 ushorts
    unsigned short* wp = wb + 32768;                       //   4096 ushorts
    prep_weights<<<656, 256, 0, stream>>>(
        (const float*)d_in[9], (const float*)d_in[10],
        (const float*)d_in[7], (const float*)d_in[15], wd, wb, wp);
    social_lstm_mfma<<<16, NTHR, 0, stream>>>(
        (const float*)d_in[0],   // past_traj
        (const float*)d_in[1],   // past_traj_rel
        (const int*)  d_in[2],   // ts mask
        (const int*)  d_in[4],   // same_scene_mask
        (const float*)d_in[5],   // pos_W
        (const float*)d_in[6],   // pos_b
        (const float*)d_in[8],   // soc_b
        (const float*)d_in[11],  // bih
        (const float*)d_in[12],  // bhh
        (const float*)d_in[13],  // h0
        (const float*)d_in[14],  // c0
        (const float*)d_in[16],  // pred_b
        wd, wb, wp,
        (float*)d_out);
}

// Round 7
// 321.425 us; speedup vs baseline: 1.0086x; 1.0086x over previous
//
#include <hip/hip_runtime.h>

#define NAGENT 64
#define HID    128
#define TOBS   8
#define PREDL  12
#define NTHR   1024
#define XP     264           // sh_X row pitch (ushort)
#define PP     264
#define S2P    264

typedef __attribute__((ext_vector_type(8))) short bf16x8;
typedef __attribute__((ext_vector_type(4))) short bf16x4;
typedef __attribute__((ext_vector_type(4))) float f32x4;
typedef __attribute__((ext_vector_type(4))) int   i32x4;

__device__ __forceinline__ unsigned short f2bf(float f) {
    unsigned int x = __float_as_uint(f);
    unsigned int r = (x + 0x7fffu + ((x >> 16) & 1u)) >> 16;   // RNE
    return (unsigned short)r;
}
__device__ __forceinline__ float bf2f(unsigned short u) {
    return __uint_as_float(((unsigned int)u) << 16);
}
__device__ __forceinline__ float sigmf(float x) {
    return __builtin_amdgcn_rcpf(1.0f + __expf(-x));
}
__device__ __forceinline__ float tanhf_fast(float x) {
    x = fminf(fmaxf(x, -15.0f), 15.0f);
    float e = __expf(2.0f * x);
    return (e - 1.0f) * __builtin_amdgcn_rcpf(e + 1.0f);
}

// ---------------- prep: pack weights into bf16 MFMA B-fragment layouts ----------------
// wd (D): B[k][n], k 0..255 = [et|at|h], n 0..511 = g*128+d (gate-major).
//   idx = ((nt*8+kt)*64+l)*8+e ; k = kt*32+(l>>4)*8+e ; n = nt*16+(l&15)
// wb (B): B[k][r], k 0..127 (h), r = e*4+g (16 nt x 4 kt)
// wp (proj): B[k][n], k 0..127 (h), n 0..15 (cols >=5 zero); hi (frags 0..3) + lo (4..7)
__global__ void prep_weights(const float* __restrict__ Wih, const float* __restrict__ Whh,
                             const float* __restrict__ socW, const float* __restrict__ predW,
                             unsigned short* __restrict__ wd, unsigned short* __restrict__ wb,
                             unsigned short* __restrict__ wp) {
    int idx = blockIdx.x * 256 + threadIdx.x;
    if (idx < 131072) {
        int e = idx & 7, l = (idx >> 3) & 63, t = idx >> 9;   // t = nt*8+kt
        int kt = t & 7, nt = t >> 3;
        int k = kt * 32 + ((l >> 4) << 3) + e;
        int n = nt * 16 + (l & 15);                           // n = g*128+d
        float v = (k < 128) ? Wih[n * 128 + k] : Whh[n * 128 + (k - 128)];
        wd[idx] = f2bf(v);
    } else if (idx < 163840) {
        int i2 = idx - 131072;
        int e = i2 & 7, l = (i2 >> 3) & 63, t = i2 >> 9;      // t = nt*4+kt
        int kt = t & 3, nt = t >> 2;
        int k = kt * 32 + ((l >> 4) << 3) + e;
        int r = nt * 16 + (l & 15);
        wb[i2] = f2bf(socW[(r >> 2) * 512 + (r & 3) * 128 + k]);
    } else if (idx < 167936) {
        int i3 = idx - 163840;
        int e = i3 & 7, l = (i3 >> 3) & 63, f = i3 >> 9;      // f = half*4+kt
        int kt = f & 3, half = f >> 2;
        int k = kt * 32 + ((l >> 4) << 3) + e;
        int n = l & 15;
        float v = (n < 5) ? predW[n * 128 + k] : 0.0f;
        unsigned short hi = f2bf(v);
        wp[i3] = half ? f2bf(v - bf2f(hi)) : hi;
    }
}

// ---------------- main: one block per 64-agent scene, 16 waves ----------------
// amdgpu_waves_per_eu(4,4): pin EXACTLY 4 waves/EU (one 16-wave block per CU) so the
// allocator gets the full 128-VGPR budget. __launch_bounds__(1024,4) only set the
// MINIMUM; the allocator still targeted 8 waves/EU, capped at 64 VGPR, and spilled
// ~1.7MB/launch (WRITE_SIZE 2064KB vs 344KB real output). R6 lesson.
__global__ __launch_bounds__(NTHR)
__attribute__((amdgpu_waves_per_eu(4, 4)))
void social_lstm_mfma(
    const float* __restrict__ past_traj, const float* __restrict__ past_traj_rel,
    const int* __restrict__ ts_mask, const int* __restrict__ scene_in,
    const float* __restrict__ pos_W, const float* __restrict__ pos_b,
    const float* __restrict__ soc_b,
    const float* __restrict__ bih, const float* __restrict__ bhh,
    const float* __restrict__ h0, const float* __restrict__ c0,
    const float* __restrict__ pred_b,
    const unsigned short* __restrict__ wd, const unsigned short* __restrict__ wb,
    const unsigned short* __restrict__ wp,
    float* __restrict__ out)
{
    __shared__ __align__(16) unsigned short sh_X[NAGENT][XP];   // 0..63 et | 64..127 at | 128..255 h
    __shared__ __align__(16) unsigned short sh_P[NAGENT][PP];   // P[i][g*64+j] bf16 0/1
    __shared__ __align__(16) unsigned short sh_S2[NAGENT][S2P]; // S2[e][g*64+j] bf16
    __shared__ float sh_px[NAGENT], sh_py[NAGENT], sh_rx[NAGENT], sh_ry[NAGENT];
    __shared__ float sh_o[5][NAGENT];
    __shared__ __align__(16) int sh_act[NAGENT];
    __shared__ int sh_scene[NAGENT];

    const int tid  = threadIdx.x;
    const int lane = tid & 63;
    const int wv   = __builtin_amdgcn_readfirstlane(tid >> 6);  // 0..15
    const int gbase = blockIdx.x * NAGENT;
    const int c16 = lane & 15;
    const int q4  = lane >> 4;

    // wave roles
    const int sub8 = wv & 7;      // D: gate-free n-group ngd | B: r-tile pair ntp
    const int mjg  = wv >> 3;     // M-half (agents 32*mjg .. +31) for D and B
    const int dim  = sub8 * 16 + c16;          // this thread's hidden dim (D pointwise)

    // ---- Phase-B weights resident (8 frags = 32 VGPR) ----
    bf16x8 wbf[2][4];
    {
        const bf16x8* wbv = (const bf16x8*)wb;
        #pragma unroll
        for (int s = 0; s < 2; ++s)
            #pragma unroll
            for (int kt = 0; kt < 4; ++kt)
                wbf[s][kt] = wbv[((2 * sub8 + s) * 4 + kt) * 64 + lane];
    }
    const float bs0 = bih[0 * 128 + dim] + bhh[0 * 128 + dim];
    const float bs1 = bih[1 * 128 + dim] + bhh[1 * 128 + dim];
    const float bs2 = bih[2 * 128 + dim] + bhh[2 * 128 + dim];
    const float bs3 = bih[3 * 128 + dim] + bhh[3 * 128 + dim];
    float c_reg[8];
    {
        const float cz = c0[dim];
        #pragma unroll
        for (int u = 0; u < 8; ++u) c_reg[u] = cz;
    }
    for (int p = tid; p < NAGENT * HID; p += NTHR) {
        int a = p >> 7, d = p & 127;
        sh_X[a][128 + d] = f2bf(h0[d]);
    }
    if (tid < NAGENT) {
        sh_scene[tid] = scene_in[gbase + tid];
        const int ig = gbase + tid;
        sh_px[tid] = past_traj[(ig * TOBS + 0) * 2 + 0];
        sh_py[tid] = past_traj[(ig * TOBS + 0) * 2 + 1];
        sh_rx[tid] = past_traj_rel[(ig * TOBS + 0) * 2 + 0];
        sh_ry[tid] = past_traj_rel[(ig * TOBS + 0) * 2 + 1];
        sh_act[tid] = (ts_mask[ig * TOBS + 0] == 1) ? 1 : 0;
    }
    __syncthreads();

    for (int step = 0; step < TOBS + PREDL; ++step) {
        if (step >= TOBS) {
            // ---- proj (waves 0..3, MFMA, pred_W bf16 hi+lo): o = h @ predW^T + pred_b ----
            if (wv < 4) {
                const bf16x8* wpv = (const bf16x8*)wp;
                f32x4 pa = (f32x4){0.f, 0.f, 0.f, 0.f};
                #pragma unroll
                for (int kt = 0; kt < 4; ++kt) {
                    const bf16x8 a = *(const bf16x8*)&sh_X[wv * 16 + c16][128 + kt * 32 + q4 * 8];
                    pa = __builtin_amdgcn_mfma_f32_16x16x32_bf16(a, wpv[kt * 64 + lane], pa, 0, 0, 0);
                    pa = __builtin_amdgcn_mfma_f32_16x16x32_bf16(a, wpv[(4 + kt) * 64 + lane], pa, 0, 0, 0);
                }
                if (c16 < 5) {
                    const float pb = pred_b[c16];
                    #pragma unroll
                    for (int rr = 0; rr < 4; ++rr)
                        sh_o[c16][wv * 16 + q4 * 4 + rr] = pa[rr] + pb;
                }
            }
            __syncthreads();
            if (tid < NAGENT) {
                const int i = tid;
                const float rx = sh_o[0][i], ry = sh_o[1][i];
                const float px = sh_px[i] + rx, py = sh_py[i] + ry;
                sh_px[i] = px; sh_py[i] = py;
                sh_rx[i] = rx; sh_ry[i] = ry;
                const float m = sh_act[i] ? 1.0f : 0.0f;
                const int p = step - TOBS;
                const int ig = gbase + i;
                float* po = out + (ig * PREDL + p) * 5;
                #pragma unroll
                for (int q = 0; q < 5; ++q) po[q] = m * sh_o[q][i];
                float* pt = out + 61440 + (ig * PREDL + p) * 2;
                pt[0] = m * px; pt[1] = m * py;
            }
            __syncthreads();
        }

        // ==== R1: Phase A (P one-hot), et, Phase B (S2 via MFMA, resident weights) ====
        #pragma unroll
        for (int it = 0; it < 4; ++it) {
            const int p = it * NTHR + tid;
            const int i = p >> 6, j = p & 63;     // i wave-uniform, j = lane
            const float dx = sh_px[j] - sh_px[i];
            const float dy = sh_py[j] - sh_py[i];
            const bool within = (dx < 0.99f) & (dx > -0.99f) & (dy < 0.99f) & (dy > -0.99f);
            const bool pair = within && (i != j) && (sh_scene[i] == sh_scene[j])
                              && sh_act[i] && sh_act[j];
            const int gid = ((dx >= 0.f) ? 2 : 0) + ((dy >= 0.f) ? 1 : 0);
            #pragma unroll
            for (int g = 0; g < 4; ++g)
                sh_P[i][g * 64 + j] = (pair && gid == g) ? (unsigned short)0x3f80
                                                         : (unsigned short)0;
        }
        if (wv < 8) {   // et: wave wv -> embed dims wv*8..+7, one b128 write per lane
            const float rx = sh_rx[lane], ry = sh_ry[lane];
            bf16x8 ev;
            #pragma unroll
            for (int u = 0; u < 8; ++u) {
                const int e = wv * 8 + u;
                ev[u] = (short)f2bf(fmaxf(pos_b[e] + rx * pos_W[2 * e] + ry * pos_W[2 * e + 1], 0.f));
            }
            *(bf16x8*)&sh_X[lane][wv * 8] = ev;
        }
        {   // Phase B: wave (mjg, ntp=sub8) -> r-tiles {2ntp,2ntp+1}, agents mjg-half
            f32x4 bac[2][2];   // [mjl][s]
            #pragma unroll
            for (int a = 0; a < 2; ++a) { bac[a][0] = (f32x4){0,0,0,0}; bac[a][1] = (f32x4){0,0,0,0}; }
            #pragma unroll
            for (int kt = 0; kt < 4; ++kt) {
                const bf16x8 a0 = *(const bf16x8*)&sh_X[(2 * mjg + 0) * 16 + c16][128 + kt * 32 + q4 * 8];
                const bf16x8 a1 = *(const bf16x8*)&sh_X[(2 * mjg + 1) * 16 + c16][128 + kt * 32 + q4 * 8];
                #pragma unroll
                for (int s = 0; s < 2; ++s) {
                    bac[0][s] = __builtin_amdgcn_mfma_f32_16x16x32_bf16(a0, wbf[s][kt], bac[0][s], 0, 0, 0);
                    bac[1][s] = __builtin_amdgcn_mfma_f32_16x16x32_bf16(a1, wbf[s][kt], bac[1][s], 0, 0, 0);
                }
            }
            #pragma unroll
            for (int mjl = 0; mjl < 2; ++mjl)
                #pragma unroll
                for (int s = 0; s < 2; ++s) {
                    const int r = (2 * sub8 + s) * 16 + c16;
                    const int e = r >> 2, g = r & 3;
                    bf16x4 pk;
                    #pragma unroll
                    for (int i = 0; i < 4; ++i) pk[i] = (short)f2bf(bac[mjl][s][i]);
                    *(bf16x4*)&sh_S2[e][g * 64 + (2 * mjg + mjl) * 16 + q4 * 4] = pk;
                }
        }
        __syncthreads();

        // ==== R2: C2 (MFMA): at = relu(P @ S2^T + soc_b); wave = one 16x16 tile ====
        {
            const int mt = wv & 3, nt = wv >> 2;
            f32x4 cac = (f32x4){0.f, 0.f, 0.f, 0.f};
            #pragma unroll
            for (int kt = 0; kt < 8; ++kt) {
                const bf16x8 a = *(const bf16x8*)&sh_P[mt * 16 + c16][kt * 32 + q4 * 8];
                const bf16x8 b = *(const bf16x8*)&sh_S2[nt * 16 + c16][kt * 32 + q4 * 8];
                cac = __builtin_amdgcn_mfma_f32_16x16x32_bf16(a, b, cac, 0, 0, 0);
            }
            const int e = nt * 16 + c16;
            const float sb = soc_b[e];
            #pragma unroll
            for (int rr = 0; rr < 4; ++rr)
                sh_X[mt * 16 + q4 * 4 + rr][64 + e] = f2bf(fmaxf(cac[rr] + sb, 0.f));
        }
        __syncthreads();

        // ==== R3: D (MFMA, gate-major, B streamed from L2) + in-lane pointwise ====
        float hn_st[8];
        unsigned int hm = 0;
        {
            const bf16x8* wdv = (const bf16x8*)wd;
            f32x4 acc[2][4];   // [mjl][g]
            #pragma unroll
            for (int a = 0; a < 2; ++a)
                #pragma unroll
                for (int g = 0; g < 4; ++g) acc[a][g] = (f32x4){0.f, 0.f, 0.f, 0.f};
            #pragma unroll 2
            for (int kt = 0; kt < 8; ++kt) {
                const bf16x8 a0 = *(const bf16x8*)&sh_X[(2 * mjg + 0) * 16 + c16][kt * 32 + q4 * 8];
                const bf16x8 a1 = *(const bf16x8*)&sh_X[(2 * mjg + 1) * 16 + c16][kt * 32 + q4 * 8];
                #pragma unroll
                for (int g = 0; g < 4; ++g) {
                    const bf16x8 b = wdv[((g * 8 + sub8) * 8 + kt) * 64 + lane];
                    acc[0][g] = __builtin_amdgcn_mfma_f32_16x16x32_bf16(a0, b, acc[0][g], 0, 0, 0);
                    acc[1][g] = __builtin_amdgcn_mfma_f32_16x16x32_bf16(a1, b, acc[1][g], 0, 0, 0);
                }
            }
            #pragma unroll
            for (int mjl = 0; mjl < 2; ++mjl) {
                const i32x4 a4 = *(const i32x4*)&sh_act[(2 * mjg + mjl) * 16 + q4 * 4];
                #pragma unroll
                for (int rr = 0; rr < 4; ++rr) {
                    const float zi = acc[mjl][0][rr] + bs0;
                    const float zf = acc[mjl][1][rr] + bs1;
                    const float zg = acc[mjl][2][rr] + bs2;
                    const float zo = acc[mjl][3][rr] + bs3;
                    const float cold = c_reg[mjl * 4 + rr];
                    const float cn = sigmf(zf) * cold + sigmf(zi) * tanhf_fast(zg);
                    const float hn = sigmf(zo) * tanhf_fast(cn);
                    const bool act = a4[rr] != 0;
                    c_reg[mjl * 4 + rr] = act ? cn : cold;
                    hn_st[mjl * 4 + rr] = hn;
                    hm |= (act ? 1u : 0u) << (mjl * 4 + rr);
                }
            }
        }
        __syncthreads();   // all waves done reading sh_X before h overwrite

        // ==== h write-back (+ next obs frame load) ====
        #pragma unroll
        for (int u = 0; u < 8; ++u) {
            if (hm & (1u << u)) {
                const int mjl = u >> 2, rr = u & 3;
                sh_X[(2 * mjg + mjl) * 16 + q4 * 4 + rr][128 + dim] = f2bf(hn_st[u]);
            }
        }
        if (step + 1 < TOBS && tid < NAGENT) {
            const int ig = gbase + tid;
            sh_px[tid] = past_traj[(ig * TOBS + step + 1) * 2 + 0];
            sh_py[tid] = past_traj[(ig * TOBS + step + 1) * 2 + 1];
            sh_rx[tid] = past_traj_rel[(ig * TOBS + step + 1) * 2 + 0];
            sh_ry[tid] = past_traj_rel[(ig * TOBS + step + 1) * 2 + 1];
            sh_act[tid] = (ts_mask[ig * TOBS + step + 1] == 1) ? 1 : 0;
        }
        __syncthreads();
    }
}

extern "C" void kernel_launch(void* const* d_in, const int* in_sizes, int n_in,
                              void* d_out, int out_size, void* d_ws, size_t ws_size,
                              hipStream_t stream) {
    (void)in_sizes; (void)n_in; (void)out_size; (void)ws_size;
    unsigned short* wd = (unsigned short*)d_ws;            // 131072 ushorts
    unsigned short* wb = wd + 131072;                      //  32768 ushorts
    unsigned short* wp = wb + 32768;                       //   4096 ushorts
    prep_weights<<<656, 256, 0, stream>>>(
        (const float*)d_in[9], (const float*)d_in[10],
        (const float*)d_in[7], (const float*)d_in[15], wd, wb, wp);
    social_lstm_mfma<<<16, NTHR, 0, stream>>>(
        (const float*)d_in[0],   // past_traj
        (const float*)d_in[1],   // past_traj_rel
        (const int*)  d_in[2],   // ts mask
        (const int*)  d_in[4],   // same_scene_mask
        (const float*)d_in[5],   // pos_W
        (const float*)d_in[6],   // pos_b
        (const float*)d_in[8],   // soc_b
        (const float*)d_in[11],  // bih
        (const float*)d_in[12],  // bhh
        (const float*)d_in[13],  // h0
        (const float*)d_in[14],  // c0
        (const float*)d_in[16],  // pred_b
        wd, wb, wp,
        (float*)d_out);
}

// Round 8
// 290.160 us; speedup vs baseline: 1.1172x; 1.1077x over previous
//
#include <hip/hip_runtime.h>

#define NAGENT 64
#define HID    128
#define TOBS   8
#define PREDL  12
#define NTHR   1024
#define XP     264           // sh_X row pitch (ushort): rows 16B-aligned (528B)
#define PP     264           // sh_P row pitch
#define SP2    264           // sh_S row pitch

typedef __attribute__((ext_vector_type(8))) short bf16x8;
typedef __attribute__((ext_vector_type(4))) short bf16x4;
typedef __attribute__((ext_vector_type(4))) float f32x4;
typedef __attribute__((ext_vector_type(2))) unsigned int u32x2;

__device__ __forceinline__ unsigned short f2bf(float f) {
    unsigned int x = __float_as_uint(f);
    unsigned int r = (x + 0x7fffu + ((x >> 16) & 1u)) >> 16;   // RNE
    return (unsigned short)r;
}
__device__ __forceinline__ float bf2f(unsigned short u) {
    return __uint_as_float(((unsigned int)u) << 16);
}
__device__ __forceinline__ float sigmf(float x) {
    return __builtin_amdgcn_rcpf(1.0f + __expf(-x));
}
__device__ __forceinline__ float tanhf_fast(float x) {
    x = fminf(fmaxf(x, -15.0f), 15.0f);
    float e = __expf(2.0f * x);
    return (e - 1.0f) * __builtin_amdgcn_rcpf(e + 1.0f);
}
__device__ __forceinline__ float sel4(float a0, float a1, float a2, float a3, int k) {
    float lo = (k & 1) ? a1 : a0;
    float hi = (k & 1) ? a3 : a2;
    return (k & 2) ? hi : lo;
}

// ---------------- prep: pack weights into bf16 MFMA B-fragment layouts ----------------
// wd (D): B[k][n], k 0..255 ([et|at|h]), n 0..511 INTERLEAVED n = d*4+g (R3 layout).
// wb (B): B[k][r], k 0..127 (h), r = e*4+g (16 nt x 4 kt)
// wp (proj): B[k][n], k 0..127 (h), n 0..15 (cols >=5 zero); hi (frags 0..3) + lo (4..7)
__global__ void prep_weights(const float* __restrict__ Wih, const float* __restrict__ Whh,
                             const float* __restrict__ socW, const float* __restrict__ predW,
                             unsigned short* __restrict__ wd, unsigned short* __restrict__ wb,
                             unsigned short* __restrict__ wp) {
    int idx = blockIdx.x * 256 + threadIdx.x;
    if (idx < 131072) {
        int e = idx & 7, l = (idx >> 3) & 63, t = idx >> 9;   // t = nt*8+kt
        int kt = t & 7, nt = t >> 3;
        int k = kt * 32 + ((l >> 4) << 3) + e;
        int n = nt * 16 + (l & 15);
        int d = n >> 2, g = n & 3;                            // n = d*4+g
        int row = g * 128 + d;
        float v = (k < 128) ? Wih[row * 128 + k] : Whh[row * 128 + (k - 128)];
        wd[idx] = f2bf(v);
    } else if (idx < 163840) {
        int i2 = idx - 131072;
        int e = i2 & 7, l = (i2 >> 3) & 63, t = i2 >> 9;      // t = nt*4+kt
        int kt = t & 3, nt = t >> 2;
        int k = kt * 32 + ((l >> 4) << 3) + e;
        int r = nt * 16 + (l & 15);
        int eo = r >> 2, g = r & 3;
        wb[i2] = f2bf(socW[eo * 512 + g * 128 + k]);
    } else if (idx < 167936) {
        int i3 = idx - 163840;
        int e = i3 & 7, l = (i3 >> 3) & 63, f = i3 >> 9;      // f = half*4+kt
        int kt = f & 3, half = f >> 2;
        int k = kt * 32 + ((l >> 4) << 3) + e;
        int n = l & 15;
        float v = (n < 5) ? predW[n * 128 + k] : 0.0f;
        unsigned short hi = f2bf(v);
        wp[i3] = half ? f2bf(v - bf2f(hi)) : hi;
    }
}

// ---------------- main: one block per 64-agent scene, 16 waves ----------------
__global__ __launch_bounds__(NTHR) void social_lstm_mfma(
    const float* __restrict__ past_traj, const float* __restrict__ past_traj_rel,
    const int* __restrict__ ts_mask, const int* __restrict__ scene_in,
    const float* __restrict__ pos_W, const float* __restrict__ pos_b,
    const float* __restrict__ soc_b,
    const float* __restrict__ bih, const float* __restrict__ bhh,
    const float* __restrict__ h0, const float* __restrict__ c0,
    const float* __restrict__ pred_b,
    const unsigned short* __restrict__ wd, const unsigned short* __restrict__ wb,
    const unsigned short* __restrict__ wp,
    float* __restrict__ out)
{
    __shared__ __align__(16) unsigned short sh_X[NAGENT][XP];  // 0..63 et | 64..127 at | 128..255 h
    __shared__ __align__(16) unsigned short sh_P[NAGENT][PP];  // P[i][j*4+g] bf16 0/1
    __shared__ __align__(16) unsigned short sh_S[NAGENT][SP2]; // S[j][r], r = e*4+g
    __shared__ float sh_px[NAGENT], sh_py[NAGENT], sh_rx[NAGENT], sh_ry[NAGENT];
    __shared__ float sh_o[5][NAGENT];
    __shared__ int   sh_act[NAGENT], sh_scene[NAGENT];

    const int tid  = threadIdx.x;
    const int lane = tid & 63;
    const int wv   = __builtin_amdgcn_readfirstlane(tid >> 6);  // 0..15
    const int gbase = blockIdx.x * NAGENT;
    const int c16 = lane & 15;   // tile col
    const int q4  = lane >> 4;   // quad
    const int go  = c16 & 3;     // owned gate (D pointwise)
    const int dq  = c16 >> 2;    // dim-within-ntile

    // per-wave geometry: phase D N-tiles 2wv, 2wv+1 (interleaved n = d*4+g)
    float bs[2], c_st[4][2], hnew[4][2];
    int dimv[2];
    #pragma unroll
    for (int s = 0; s < 2; ++s) {
        const int n = (2 * wv + s) * 16 + c16;
        const int d = n >> 2, g = n & 3;
        bs[s] = bih[g * 128 + d] + bhh[g * 128 + d];
        dimv[s] = (2 * wv + s) * 4 + dq;
        #pragma unroll
        for (int mj = 0; mj < 4; ++mj) c_st[mj][s] = c0[dimv[s]];
    }
    for (int p = tid; p < NAGENT * HID; p += NTHR) {
        int a = p >> 7, d = p & 127;
        sh_X[a][128 + d] = f2bf(h0[d]);
    }
    if (tid < NAGENT) sh_scene[tid] = scene_in[gbase + tid];
    __syncthreads();

    const bf16x8* wdp = (const bf16x8*)wd + (2 * wv * 8) * 64 + lane;  // +kt*64, +512 for nt+1
    const bf16x8* wbp = (const bf16x8*)wb + (wv * 4) * 64 + lane;      // +kt*64
    const unsigned short* xaD = &sh_X[c16][q4 * 8];        // A-frag base, phase D (k 0..255)
    const unsigned short* xaB = &sh_X[c16][128 + q4 * 8];  // A-frag base, phase B (h region)

    for (int step = 0; step < TOBS + PREDL; ++step) {
        if (step < TOBS) {
            if (tid < NAGENT) {
                const int ig = gbase + tid;
                sh_px[tid] = past_traj[(ig * TOBS + step) * 2 + 0];
                sh_py[tid] = past_traj[(ig * TOBS + step) * 2 + 1];
                sh_rx[tid] = past_traj_rel[(ig * TOBS + step) * 2 + 0];
                sh_ry[tid] = past_traj_rel[(ig * TOBS + step) * 2 + 1];
                sh_act[tid] = (ts_mask[ig * TOBS + step] == 1) ? 1 : 0;
            }
        } else {
            // ---- proj (waves 0..3, MFMA, pred_W bf16 hi+lo): o = h @ predW^T + pred_b ----
            if (wv < 4) {
                const bf16x8* wpv = (const bf16x8*)wp;
                f32x4 pa = (f32x4){0.f, 0.f, 0.f, 0.f};
                #pragma unroll
                for (int kt = 0; kt < 4; ++kt) {
                    const bf16x8 a = *(const bf16x8*)&sh_X[wv * 16 + c16][128 + kt * 32 + q4 * 8];
                    pa = __builtin_amdgcn_mfma_f32_16x16x32_bf16(a, wpv[kt * 64 + lane], pa, 0, 0, 0);
                    pa = __builtin_amdgcn_mfma_f32_16x16x32_bf16(a, wpv[(4 + kt) * 64 + lane], pa, 0, 0, 0);
                }
                if (c16 < 5) {
                    const float pb = pred_b[c16];
                    #pragma unroll
                    for (int rr = 0; rr < 4; ++rr)
                        sh_o[c16][wv * 16 + q4 * 4 + rr] = pa[rr] + pb;
                }
            }
            __syncthreads();
            if (tid < NAGENT) {
                const int i = tid;
                const float rx = sh_o[0][i], ry = sh_o[1][i];
                const float px = sh_px[i] + rx, py = sh_py[i] + ry;
                sh_px[i] = px; sh_py[i] = py;
                sh_rx[i] = rx; sh_ry[i] = ry;
                const float m = sh_act[i] ? 1.0f : 0.0f;
                const int p = step - TOBS;
                const int ig = gbase + i;
                float* po = out + (ig * PREDL + p) * 5;
                #pragma unroll
                for (int q = 0; q < 5; ++q) po[q] = m * sh_o[q][i];
                float* pt = out + 61440 + (ig * PREDL + p) * 2;
                pt[0] = m * px; pt[1] = m * py;
            }
        }
        __syncthreads();

        // ==== R1: Phase A (P one-hot, 8B packed, k'=j*4+g), et, Phase B -> S[j][r] ====
        #pragma unroll
        for (int it = 0; it < 4; ++it) {
            const int p = it * NTHR + tid;
            const int i = p >> 6, j = p & 63;     // i wave-uniform, j = lane
            const float dx = sh_px[j] - sh_px[i];
            const float dy = sh_py[j] - sh_py[i];
            const bool within = (dx < 0.99f) & (dx > -0.99f) & (dy < 0.99f) & (dy > -0.99f);
            const bool pair = within && (i != j) && (sh_scene[i] == sh_scene[j])
                              && sh_act[i] && sh_act[j];
            const int gid = ((dx >= 0.f) ? 2 : 0) + ((dy >= 0.f) ? 1 : 0);
            unsigned int w0 = 0, w1 = 0;
            if (pair) {
                if (gid == 0) w0 = 0x3f80u;
                else if (gid == 1) w0 = 0x3f800000u;
                else if (gid == 2) w1 = 0x3f80u;
                else w1 = 0x3f800000u;
            }
            u32x2 w; w[0] = w0; w[1] = w1;
            *(u32x2*)&sh_P[i][j * 4] = w;
        }
        {   // et: wave wv -> embed dims wv*4.., lane = agent
            const float rx = sh_rx[lane], ry = sh_ry[lane];
            const int e0 = wv * 4;
            #pragma unroll
            for (int u = 0; u < 4; ++u) {
                const int e = e0 + u;
                sh_X[lane][e] = f2bf(fmaxf(pos_b[e] + rx * pos_W[e * 2] + ry * pos_W[e * 2 + 1], 0.f));
            }
        }
        {   // Phase B (MFMA): S[j][r], wave = r-tile wv; store ROW-NATURAL (no col scatter)
            f32x4 acc2[4];
            #pragma unroll
            for (int mj = 0; mj < 4; ++mj) acc2[mj] = (f32x4){0.f, 0.f, 0.f, 0.f};
            #pragma unroll
            for (int kt = 0; kt < 4; ++kt) {
                const bf16x8 b = wbp[kt * 64];
                #pragma unroll
                for (int mj = 0; mj < 4; ++mj) {
                    const bf16x8 a = *(const bf16x8*)(xaB + mj * 16 * XP + kt * 32);
                    acc2[mj] = __builtin_amdgcn_mfma_f32_16x16x32_bf16(a, b, acc2[mj], 0, 0, 0);
                }
            }
            const int rcol = wv * 16 + c16;
            #pragma unroll
            for (int mj = 0; mj < 4; ++mj)
                #pragma unroll
                for (int rr = 0; rr < 4; ++rr)
                    sh_S[mj * 16 + q4 * 4 + rr][rcol] = f2bf(acc2[mj][rr]);
        }
        __syncthreads();

        // ==== R2: C2 (MFMA): at = relu(P @ S + soc_b) over k'=(j,g) ====
        {
            const int mt = wv & 3, nt = wv >> 2;
            const int cb = 4 * (nt * 16 + c16);         // col base in S (ushort idx)
            f32x4 cac = (f32x4){0.f, 0.f, 0.f, 0.f};
            #pragma unroll
            for (int kt = 0; kt < 8; ++kt) {
                const bf16x8 a = *(const bf16x8*)&sh_P[mt * 16 + c16][kt * 32 + q4 * 8];
                const int j0 = kt * 8 + q4 * 2;
                const bf16x4 lo = *(const bf16x4*)&sh_S[j0][cb];
                const bf16x4 hi = *(const bf16x4*)&sh_S[j0 + 1][cb];
                const bf16x8 b = __builtin_shufflevector(lo, hi, 0, 1, 2, 3, 4, 5, 6, 7);
                cac = __builtin_amdgcn_mfma_f32_16x16x32_bf16(a, b, cac, 0, 0, 0);
            }
            const int e = nt * 16 + c16;
            const float sb = soc_b[e];
            #pragma unroll
            for (int rr = 0; rr < 4; ++rr)
                sh_X[mt * 16 + q4 * 4 + rr][64 + e] = f2bf(fmaxf(cac[rr] + sb, 0.f));
        }
        __syncthreads();

        // ==== R3: D (MFMA, n=d*4+g interleaved, weights streamed) + shfl pointwise ====
        {
            f32x4 acc[4][2];
            #pragma unroll
            for (int mj = 0; mj < 4; ++mj) {
                acc[mj][0] = (f32x4){0.f, 0.f, 0.f, 0.f};
                acc[mj][1] = (f32x4){0.f, 0.f, 0.f, 0.f};
            }
            #pragma unroll 2
            for (int kt = 0; kt < 8; ++kt) {
                const bf16x8 b0 = wdp[kt * 64];
                const bf16x8 b1 = wdp[kt * 64 + 512];
                #pragma unroll
                for (int mj = 0; mj < 4; ++mj) {
                    const bf16x8 a = *(const bf16x8*)(xaD + mj * 16 * XP + kt * 32);
                    acc[mj][0] = __builtin_amdgcn_mfma_f32_16x16x32_bf16(a, b0, acc[mj][0], 0, 0, 0);
                    acc[mj][1] = __builtin_amdgcn_mfma_f32_16x16x32_bf16(a, b1, acc[mj][1], 0, 0, 0);
                }
            }
            // pointwise LSTM: 4-lane gate exchange, lane owns agent-subrow i==go
            #pragma unroll
            for (int mj = 0; mj < 4; ++mj) {
                const int a = mj * 16 + q4 * 4 + go;
                const bool act = sh_act[a] != 0;
                #pragma unroll
                for (int s = 0; s < 2; ++s) {
                    const float z0 = acc[mj][s][0] + bs[s];
                    const float z1 = acc[mj][s][1] + bs[s];
                    const float z2 = acc[mj][s][2] + bs[s];
                    const float z3 = acc[mj][s][3] + bs[s];
                    const float s0 = sel4(z0, z1, z2, z3, go);
                    const float s1 = sel4(z0, z1, z2, z3, go ^ 1);
                    const float s2 = sel4(z0, z1, z2, z3, go ^ 2);
                    const float s3 = sel4(z0, z1, z2, z3, go ^ 3);
                    const float t1 = __shfl_xor(s1, 1, 64);
                    const float t2 = __shfl_xor(s2, 2, 64);
                    const float t3 = __shfl_xor(s3, 3, 64);
                    const float zi = sel4(s0, t1, t2, t3, go);
                    const float zf = sel4(s0, t1, t2, t3, go ^ 1);
                    const float zg = sel4(s0, t1, t2, t3, go ^ 2);
                    const float zo = sel4(s0, t1, t2, t3, go ^ 3);
                    const float cold = c_st[mj][s];
                    const float cn = sigmf(zf) * cold + sigmf(zi) * tanhf_fast(zg);
                    const float hn = sigmf(zo) * tanhf_fast(cn);
                    c_st[mj][s] = act ? cn : cold;
                    const float hold = bf2f(sh_X[a][128 + dimv[s]]);
                    hnew[mj][s] = act ? hn : hold;
                }
            }
        }
        __syncthreads();   // everyone done reading h region
        #pragma unroll
        for (int mj = 0; mj < 4; ++mj) {
            const int a = mj * 16 + q4 * 4 + go;
            sh_X[a][128 + dimv[0]] = f2bf(hnew[mj][0]);
            sh_X[a][128 + dimv[1]] = f2bf(hnew[mj][1]);
        }
        __syncthreads();
    }
}

extern "C" void kernel_launch(void* const* d_in, const int* in_sizes, int n_in,
                              void* d_out, int out_size, void* d_ws, size_t ws_size,
                              hipStream_t stream) {
    (void)in_sizes; (void)n_in; (void)out_size; (void)ws_size;
    unsigned short* wd = (unsigned short*)d_ws;            // 131072 ushorts
    unsigned short* wb = wd + 131072;                      //  32768 ushorts
    unsigned short* wp = wb + 32768;                       //   4096 ushorts
    prep_weights<<<656, 256, 0, stream>>>(
        (const float*)d_in[9], (const float*)d_in[10],
        (const float*)d_in[7], (const float*)d_in[15], wd, wb, wp);
    social_lstm_mfma<<<16, NTHR, 0, stream>>>(
        (const float*)d_in[0],   // past_traj
        (const float*)d_in[1],   // past_traj_rel
        (const int*)  d_in[2],   // ts mask
        (const int*)  d_in[4],   // same_scene_mask
        (const float*)d_in[5],   // pos_W
        (const float*)d_in[6],   // pos_b
        (const float*)d_in[8],   // soc_b
        (const float*)d_in[11],  // bih
        (const float*)d_in[12],  // bhh
        (const float*)d_in[13],  // h0
        (const float*)d_in[14],  // c0
        (const float*)d_in[16],  // pred_b
        wd, wb, wp,
        (float*)d_out);
}